// Round 2
// baseline (789.808 us; speedup 1.0000x reference)
//
#include <hip/hip_runtime.h>

#define NUM_CLASSES 100000
#define NUM_FEATURES 256
#define BATCH 1024
#define SCALARF 30.0f
#define EPSF 1e-12f

typedef __attribute__((ext_vector_type(4))) float float4v;
typedef __attribute__((ext_vector_type(8))) short short8;   // 8 x bf16 (4 VGPRs)
typedef __attribute__((ext_vector_type(4))) short short4v;  // 4 x bf16 (8 B)

static __device__ inline short f2bf(float f) {
    // round-to-nearest-even fp32 -> bf16 (inputs are finite randn; NaN path irrelevant)
    unsigned u = __builtin_bit_cast(unsigned, f);
    unsigned r = (u + 0x7FFFu + ((u >> 16) & 1u)) >> 16;
    return (short)r;
}

static __device__ inline float wave_reduce_sum(float s) {
#pragma unroll
    for (int off = 32; off > 0; off >>= 1) s += __shfl_xor(s, off, 64);
    return s;
}

// ---------------------------------------------------------------------------
// K1: normalize x rows -> xn (fp32) and xnb (bf16); echo targets as float32.
// One wave per row; lane holds 4 contiguous floats.
__global__ __launch_bounds__(64) void xnorm_kernel(const float* __restrict__ x,
                                                   const int* __restrict__ tgt,
                                                   float* __restrict__ xn,
                                                   short* __restrict__ xnb,
                                                   float* __restrict__ out_tgt) {
    int row = blockIdx.x;
    int lane = threadIdx.x;
    const float4v v = *(const float4v*)(x + (size_t)row * NUM_FEATURES + lane * 4);
    float s = v.x * v.x + v.y * v.y + v.z * v.z + v.w * v.w;
    s = wave_reduce_sum(s);
    float scale = 1.0f / fmaxf(sqrtf(s), EPSF);
    float4v nv = v * scale;
    *(float4v*)(xn + (size_t)row * NUM_FEATURES + lane * 4) = nv;
    short4v bv;
    bv.x = f2bf(nv.x); bv.y = f2bf(nv.y); bv.z = f2bf(nv.z); bv.w = f2bf(nv.w);
    *(short4v*)(xnb + (size_t)row * NUM_FEATURES + lane * 4) = bv;
    if (lane == 0) out_tgt[row] = (float)tgt[row];
}

// ---------------------------------------------------------------------------
// K2: per weight row: copy raw row -> out_w (new_weight baseline), and write
// normalized bf16 row -> wnb (GEMM B operand). 4 waves/block, 1 row/wave.
// out_w is write-only here -> nontemporal (keep L2 for wnb, which GEMM re-reads).
__global__ __launch_bounds__(256) void wnorm_kernel(const float* __restrict__ w,
                                                    short* __restrict__ wnb,
                                                    float* __restrict__ out_w) {
    int row = blockIdx.x * 4 + (threadIdx.x >> 6);
    int lane = threadIdx.x & 63;
    const float4v v = *(const float4v*)(w + (size_t)row * NUM_FEATURES + lane * 4);
    float s = v.x * v.x + v.y * v.y + v.z * v.z + v.w * v.w;
    s = wave_reduce_sum(s);
    float scale = 1.0f / fmaxf(sqrtf(s), EPSF);
    // raw copy (un-normalized), per reference: untouched rows keep raw values
    __builtin_nontemporal_store(v, (float4v*)(out_w + (size_t)row * NUM_FEATURES + lane * 4));
    float4v nv = v * scale;
    short4v bv;
    bv.x = f2bf(nv.x); bv.y = f2bf(nv.y); bv.z = f2bf(nv.z); bv.w = f2bf(nv.w);
    *(short4v*)(wnb + (size_t)row * NUM_FEATURES + lane * 4) = bv;
}

// ---------------------------------------------------------------------------
// K3 (fused chain+update): one wave per batch index. Block i exits unless i is
// the first occurrence of its target ("head"); heads replay their duplicate
// chain in batch order in fp32, exactly matching the sequential reference
// (distinct targets are independent; only final row state is stored).
__global__ __launch_bounds__(64) void update_kernel(const float* __restrict__ xn,
                                                    const float* __restrict__ w_raw,
                                                    const int* __restrict__ tgt,
                                                    float* __restrict__ out_w) {
    __shared__ int t[BATCH];
    int i = blockIdx.x;
    int lane = threadIdx.x;
    for (int j = lane; j < BATCH; j += 64) t[j] = tgt[j];
    __syncthreads();
    int mine = t[i];
    bool dup = false;
    for (int j = lane; j < i; j += 64)
        if (t[j] == mine) { dup = true; break; }
    if (__any(dup)) return;  // not a chain head

    float4v row = *(const float4v*)(w_raw + (size_t)mine * NUM_FEATURES + lane * 4);
    int cur = i;
    while (cur >= 0) {
        const float4v xv = *(const float4v*)(xn + (size_t)cur * NUM_FEATURES + lane * 4);
        row = row * 0.5f + xv * 0.5f;
        float s = row.x * row.x + row.y * row.y + row.z * row.z + row.w * row.w;
        s = wave_reduce_sum(s);
        float scale = 1.0f / fmaxf(sqrtf(s), EPSF);
        row = row * scale;
        // find first j > cur with t[j] == mine (uniform across lanes)
        int nx = -1;
        for (int base = cur + 1; base < BATCH; base += 64) {
            int j = base + lane;
            bool m = (j < BATCH) && (t[j] == mine);
            unsigned long long mask = __ballot(m);
            if (mask) { nx = base + (int)__builtin_ctzll(mask); break; }
        }
        cur = nx;
    }
    *(float4v*)(out_w + (size_t)mine * NUM_FEATURES + lane * 4) = row;
}

// ---------------------------------------------------------------------------
// K4: predicts = (xn @ wnb^T) * 30. M=1024, N=100000, K=256. Write-dominated.
// 128x128 block tile, EIGHT waves in 2(m)x4(n); wave tile 64m x 32n.
//   - acc shrinks to 8 float4 (32 VGPR); with A/B double buffers total ~110
//     VGPR -> __launch_bounds__(512,4) holds <=128 VGPR -> 4 waves/SIMD
//     (2x the latency hiding of the previous 2x2/64x64 shape).
//   - MFMA operands SWAPPED (mfma(b,a,acc)): lane's acc quad = 4 consecutive n
//     -> dwordx4 stores; store loop j-INNER so each row gets 128 B (a full
//     line) from back-to-back instructions.
//   - predicts stores are nontemporal: 410 MB write-only stream must not evict
//     the B panel (51 MB, reused by 8 same-XCD blocks) from L2.
// Grid: flat 6256 with XCD-contiguous swizzle (6256 % 8 == 0, bijective);
// the 8 M-blocks sharing one B-panel run back-to-back on the SAME XCD.
#define GRID_MX 8
#define GRID_NY 782
__global__ __launch_bounds__(512, 4) void gemm_kernel(const short* __restrict__ xnb,
                                                      const short* __restrict__ wnb,
                                                      float* __restrict__ out) {
    int id = blockIdx.x;
    int orig = (id & 7) * (GRID_MX * GRID_NY / 8) + (id >> 3);
    int bx = orig & 7;   // M tile (fastest in orig space -> same-by adjacent)
    int by = orig >> 3;  // N tile

    int tid = threadIdx.x;
    int lane = tid & 63;
    int wave = tid >> 6;        // 0..7
    int wm = wave & 1;          // 2 waves over M
    int wn = wave >> 1;         // 4 waves over N
    int m0 = bx * 128 + wm * 64;   // M = 1024 exactly divisible
    int n0 = by * 128 + wn * 32;   // N tail guarded at store
    int r16 = lane & 15;
    int quad = lane >> 4;

    float4v acc[4][2];
#pragma unroll
    for (int i = 0; i < 4; ++i)
#pragma unroll
        for (int j = 0; j < 2; ++j) acc[i][j] = (float4v){0.f, 0.f, 0.f, 0.f};

    const short* abase[4];
    const short* bbase[2];
#pragma unroll
    for (int i = 0; i < 4; ++i) {
        int m = m0 + i * 16 + r16;
        abase[i] = xnb + (size_t)m * NUM_FEATURES + quad * 8;
    }
#pragma unroll
    for (int j = 0; j < 2; ++j) {
        int n = n0 + j * 16 + r16;
        n = n < NUM_CLASSES ? n : (NUM_CLASSES - 1);  // tail rows clamped, discarded at store
        bbase[j] = wnb + (size_t)n * NUM_FEATURES + quad * 8;
    }

    short8 a[2][4], b[2][2];
#pragma unroll
    for (int i = 0; i < 4; ++i) a[0][i] = *(const short8*)(abase[i]);
#pragma unroll
    for (int j = 0; j < 2; ++j) b[0][j] = *(const short8*)(bbase[j]);

#pragma unroll
    for (int s = 0; s < 8; ++s) {  // K = 8 steps of 32 (fully unrolled: static buf idx)
        const int cur = s & 1;
        const int nxt = cur ^ 1;
        if (s < 7) {
            const int k0 = (s + 1) * 32;
#pragma unroll
            for (int j = 0; j < 2; ++j) b[nxt][j] = *(const short8*)(bbase[j] + k0);
#pragma unroll
            for (int i = 0; i < 4; ++i) a[nxt][i] = *(const short8*)(abase[i] + k0);
        }
#pragma unroll
        for (int i = 0; i < 4; ++i)
#pragma unroll
            for (int j = 0; j < 2; ++j)
                acc[i][j] = __builtin_amdgcn_mfma_f32_16x16x32_bf16(b[cur][j], a[cur][i],
                                                                    acc[i][j], 0, 0, 0);
    }

    // Swapped-operand C/D layout: col (lane&15) -> m-local, row (quad*4+r) -> n-local.
    // j inner: each of 16 rows receives 2 x 64 B back-to-back = one full 128 B line.
#pragma unroll
    for (int i = 0; i < 4; ++i) {
        int m = m0 + i * 16 + r16;
        float* rowp = out + (size_t)m * NUM_CLASSES;
#pragma unroll
        for (int j = 0; j < 2; ++j) {
            int nb = n0 + j * 16;
            if (nb < NUM_CLASSES) {  // 16-chunks all-in or all-out (100000 % 16 == 0)
                float4v v = acc[i][j] * SCALARF;
                __builtin_nontemporal_store(v, (float4v*)(rowp + nb + quad * 4));
            }
        }
    }
}

// ---------------------------------------------------------------------------
extern "C" void kernel_launch(void* const* d_in, const int* in_sizes, int n_in,
                              void* d_out, int out_size, void* d_ws, size_t ws_size,
                              hipStream_t stream) {
    const float* x = (const float*)d_in[0];     // [1024, 256] f32
    const int* tgt = (const int*)d_in[1];       // [1024] i32
    const float* w = (const float*)d_in[2];     // [100000, 256] f32

    float* out = (float*)d_out;
    float* out_pred = out;                                    // [1024, 100000]
    float* out_tgt = out + (size_t)BATCH * NUM_CLASSES;       // [1024] (as f32 values)
    float* out_w = out_tgt + BATCH;                           // [100000, 256]

    char* ws = (char*)d_ws;
    float* xn = (float*)ws;                                   // 1 MB fp32 x_norm
    short* xnb = (short*)(ws + (1 << 20));                    // 512 KB bf16 x_norm
    short* wnb = (short*)(ws + (1 << 20) + (1 << 19));        // 51.2 MB bf16 w_norm

    xnorm_kernel<<<BATCH, 64, 0, stream>>>(x, tgt, xn, xnb, out_tgt);
    wnorm_kernel<<<NUM_CLASSES / 4, 256, 0, stream>>>(w, wnb, out_w);
    update_kernel<<<BATCH, 64, 0, stream>>>(xn, w, tgt, out_w);
    gemm_kernel<<<GRID_MX * GRID_NY, 512, 0, stream>>>(xnb, wnb, out_pred);
}

// Round 3
// 767.887 us; speedup vs baseline: 1.0285x; 1.0285x over previous
//
#include <hip/hip_runtime.h>

#define NUM_CLASSES 100000
#define NUM_FEATURES 256
#define BATCH 1024
#define SCALARF 30.0f
#define EPSF 1e-12f

typedef __attribute__((ext_vector_type(4))) float float4v;
typedef __attribute__((ext_vector_type(8))) short short8;   // 8 x bf16 (4 VGPRs)
typedef __attribute__((ext_vector_type(4))) short short4v;  // 4 x bf16 (8 B)

static __device__ inline short f2bf(float f) {
    // round-to-nearest-even fp32 -> bf16 (inputs are finite randn; NaN path irrelevant)
    unsigned u = __builtin_bit_cast(unsigned, f);
    unsigned r = (u + 0x7FFFu + ((u >> 16) & 1u)) >> 16;
    return (short)r;
}

static __device__ inline float wave_reduce_sum(float s) {
#pragma unroll
    for (int off = 32; off > 0; off >>= 1) s += __shfl_xor(s, off, 64);
    return s;
}

// ---------------------------------------------------------------------------
// K1 (fused xnorm + wnorm): one wave per row, 4 waves/block.
//   blocks [0, 25000): weight rows 4b..4b+3 -> raw copy to out_w, normalized
//                      bf16 row to wnb.
//   blocks [25000, 25256): x rows -> normalized bf16 to xnb; lane0 echoes tgt.
// (fp32 xn is no longer materialized; update_kernel re-normalizes x inline
//  with the identical reduction -> bit-identical values.)
#define WN_BLOCKS (NUM_CLASSES / 4)
#define XN_BLOCKS (BATCH / 4)
__global__ __launch_bounds__(256) void norm_kernel(const float* __restrict__ x,
                                                   const int* __restrict__ tgt,
                                                   const float* __restrict__ w,
                                                   short* __restrict__ xnb,
                                                   short* __restrict__ wnb,
                                                   float* __restrict__ out_w,
                                                   float* __restrict__ out_tgt) {
    int wave = threadIdx.x >> 6;
    int lane = threadIdx.x & 63;
    int b = blockIdx.x;
    if (b < WN_BLOCKS) {
        int row = b * 4 + wave;
        const float4v v = *(const float4v*)(w + (size_t)row * NUM_FEATURES + lane * 4);
        float s = v.x * v.x + v.y * v.y + v.z * v.z + v.w * v.w;
        s = wave_reduce_sum(s);
        float scale = 1.0f / fmaxf(sqrtf(s), EPSF);
        // raw copy (un-normalized): untouched rows keep raw values per reference
        *(float4v*)(out_w + (size_t)row * NUM_FEATURES + lane * 4) = v;
        float4v nv = v * scale;
        short4v bv;
        bv.x = f2bf(nv.x); bv.y = f2bf(nv.y); bv.z = f2bf(nv.z); bv.w = f2bf(nv.w);
        *(short4v*)(wnb + (size_t)row * NUM_FEATURES + lane * 4) = bv;
    } else {
        int row = (b - WN_BLOCKS) * 4 + wave;   // 0..1023
        const float4v v = *(const float4v*)(x + (size_t)row * NUM_FEATURES + lane * 4);
        float s = v.x * v.x + v.y * v.y + v.z * v.z + v.w * v.w;
        s = wave_reduce_sum(s);
        float scale = 1.0f / fmaxf(sqrtf(s), EPSF);
        float4v nv = v * scale;
        short4v bv;
        bv.x = f2bf(nv.x); bv.y = f2bf(nv.y); bv.z = f2bf(nv.z); bv.w = f2bf(nv.w);
        *(short4v*)(xnb + (size_t)row * NUM_FEATURES + lane * 4) = bv;
        if (lane == 0) out_tgt[row] = (float)tgt[row];
    }
}

// ---------------------------------------------------------------------------
// K2 (chain + momentum update): one wave per batch index. Wave i exits unless
// i is the first occurrence of its target; heads replay their duplicate chain
// in batch order in fp32, matching the sequential reference exactly (distinct
// targets independent; only final row state stored). x is re-normalized inline
// with the same reduction order as K1 -> bit-identical to the old xn buffer.
// Runs AFTER K1 on the stream, so its out_w writes overwrite the raw copies.
__global__ __launch_bounds__(64) void update_kernel(const float* __restrict__ x,
                                                    const float* __restrict__ w_raw,
                                                    const int* __restrict__ tgt,
                                                    float* __restrict__ out_w) {
    __shared__ int t[BATCH];
    int i = blockIdx.x;
    int lane = threadIdx.x;
    for (int j = lane; j < BATCH; j += 64) t[j] = tgt[j];
    __syncthreads();
    int mine = t[i];
    bool dup = false;
    for (int j = lane; j < i; j += 64)
        if (t[j] == mine) { dup = true; break; }
    if (__any(dup)) return;  // not a chain head

    float4v row = *(const float4v*)(w_raw + (size_t)mine * NUM_FEATURES + lane * 4);
    int cur = i;
    while (cur >= 0) {
        const float4v xr = *(const float4v*)(x + (size_t)cur * NUM_FEATURES + lane * 4);
        float sx = xr.x * xr.x + xr.y * xr.y + xr.z * xr.z + xr.w * xr.w;
        sx = wave_reduce_sum(sx);
        float xscale = 1.0f / fmaxf(sqrtf(sx), EPSF);
        float4v xv = xr * xscale;
        row = row * 0.5f + xv * 0.5f;
        float s = row.x * row.x + row.y * row.y + row.z * row.z + row.w * row.w;
        s = wave_reduce_sum(s);
        float scale = 1.0f / fmaxf(sqrtf(s), EPSF);
        row = row * scale;
        // find first j > cur with t[j] == mine (uniform across lanes)
        int nx = -1;
        for (int base = cur + 1; base < BATCH; base += 64) {
            int j = base + lane;
            bool m = (j < BATCH) && (t[j] == mine);
            unsigned long long mask = __ballot(m);
            if (mask) { nx = base + (int)__builtin_ctzll(mask); break; }
        }
        cur = nx;
    }
    *(float4v*)(out_w + (size_t)mine * NUM_FEATURES + lane * 4) = row;
}

// ---------------------------------------------------------------------------
// K3: predicts = (xn @ wnb^T) * 30. M=1024, N=100000, K=256. Write-dominated.
// Round-1 best shape: 128x128 block tile, 4 waves in 2x2, wave tile 64x64 via
// 16 mfma 16x16x32; regular (cached) stores.
//   - MFMA operands SWAPPED (mfma(b,a,acc)): lane's acc quad = 4 consecutive n
//     -> dwordx4 stores.
//   - Epilogue i-OUTER / j-INNER: each output row receives 4 x 64 B from
//     back-to-back instructions = 256 B (2 full lines) combined in L2.
//   - K-loop: statically-indexed 2-deep register double buffer.
// Grid: flat 6256 with XCD-contiguous swizzle (6256 % 8 == 0, bijective);
// the 8 M-blocks sharing one B-panel run back-to-back on the SAME XCD.
#define GRID_MX 8
#define GRID_NY 782
__global__ __launch_bounds__(256) void gemm_kernel(const short* __restrict__ xnb,
                                                   const short* __restrict__ wnb,
                                                   float* __restrict__ out) {
    int id = blockIdx.x;
    int orig = (id & 7) * (GRID_MX * GRID_NY / 8) + (id >> 3);
    int bx = orig & 7;   // M tile (fastest in orig space -> same-by adjacent)
    int by = orig >> 3;  // N tile

    int tid = threadIdx.x;
    int lane = tid & 63;
    int wave = tid >> 6;
    int wm = wave & 1;
    int wn = wave >> 1;
    int m0 = bx * 128 + wm * 64;   // M = 1024 exactly divisible
    int n0 = by * 128 + wn * 64;   // N tail guarded at store
    int r16 = lane & 15;
    int quad = lane >> 4;

    float4v acc[4][4];
#pragma unroll
    for (int i = 0; i < 4; ++i)
#pragma unroll
        for (int j = 0; j < 4; ++j) acc[i][j] = (float4v){0.f, 0.f, 0.f, 0.f};

    const short* abase[4];
    const short* bbase[4];
#pragma unroll
    for (int i = 0; i < 4; ++i) {
        int m = m0 + i * 16 + r16;
        abase[i] = xnb + (size_t)m * NUM_FEATURES + quad * 8;
    }
#pragma unroll
    for (int j = 0; j < 4; ++j) {
        int n = n0 + j * 16 + r16;
        n = n < NUM_CLASSES ? n : (NUM_CLASSES - 1);  // tail rows clamped, discarded at store
        bbase[j] = wnb + (size_t)n * NUM_FEATURES + quad * 8;
    }

    short8 a[2][4], b[2][4];
#pragma unroll
    for (int i = 0; i < 4; ++i) a[0][i] = *(const short8*)(abase[i]);
#pragma unroll
    for (int j = 0; j < 4; ++j) b[0][j] = *(const short8*)(bbase[j]);

#pragma unroll
    for (int s = 0; s < 8; ++s) {  // K = 8 steps of 32 (fully unrolled: static buf idx)
        const int cur = s & 1;
        const int nxt = cur ^ 1;
        if (s < 7) {
            const int k0 = (s + 1) * 32;
#pragma unroll
            for (int j = 0; j < 4; ++j) b[nxt][j] = *(const short8*)(bbase[j] + k0);
#pragma unroll
            for (int i = 0; i < 4; ++i) a[nxt][i] = *(const short8*)(abase[i] + k0);
        }
#pragma unroll
        for (int i = 0; i < 4; ++i)
#pragma unroll
            for (int j = 0; j < 4; ++j)
                acc[i][j] = __builtin_amdgcn_mfma_f32_16x16x32_bf16(b[cur][j], a[cur][i],
                                                                    acc[i][j], 0, 0, 0);
    }

    // Swapped-operand C/D layout: col (lane&15) -> m-local, row (quad*4+r) -> n-local.
    // i outer / j inner: each of 16 rows gets 4 x 64 B back-to-back = 2 full lines.
#pragma unroll
    for (int i = 0; i < 4; ++i) {
        int m = m0 + i * 16 + r16;
        float* rowp = out + (size_t)m * NUM_CLASSES;
#pragma unroll
        for (int j = 0; j < 4; ++j) {
            int nb = n0 + j * 16;
            if (nb < NUM_CLASSES) {  // 16-chunks all-in or all-out (100000 % 16 == 0)
                float4v v = acc[i][j] * SCALARF;
                *(float4v*)(rowp + nb + quad * 4) = v;
            }
        }
    }
}

// ---------------------------------------------------------------------------
extern "C" void kernel_launch(void* const* d_in, const int* in_sizes, int n_in,
                              void* d_out, int out_size, void* d_ws, size_t ws_size,
                              hipStream_t stream) {
    const float* x = (const float*)d_in[0];     // [1024, 256] f32
    const int* tgt = (const int*)d_in[1];       // [1024] i32
    const float* w = (const float*)d_in[2];     // [100000, 256] f32

    float* out = (float*)d_out;
    float* out_pred = out;                                    // [1024, 100000]
    float* out_tgt = out + (size_t)BATCH * NUM_CLASSES;       // [1024] (as f32 values)
    float* out_w = out_tgt + BATCH;                           // [100000, 256]

    char* ws = (char*)d_ws;
    short* xnb = (short*)ws;                                  // 512 KB bf16 x_norm
    short* wnb = (short*)(ws + (1 << 19));                    // 51.2 MB bf16 w_norm

    norm_kernel<<<WN_BLOCKS + XN_BLOCKS, 256, 0, stream>>>(x, tgt, w, xnb, wnb, out_w, out_tgt);
    update_kernel<<<BATCH, 64, 0, stream>>>(x, w, tgt, out_w);
    gemm_kernel<<<GRID_MX * GRID_NY, 256, 0, stream>>>(xnb, wnb, out_pred);
}